// Round 2
// baseline (1489.876 us; speedup 1.0000x reference)
//
#include <hip/hip_runtime.h>
#include <cstddef>

// W-MSA fused kernel (Swin-style, shifted window, 2x2 max-pooled K/V).
// One block per window: 4096 blocks x 256 threads.
// All fp32 (no fp32 MFMA on CDNA4 -> vector ALU GEMMs).
//
// Layout notes:
//  - XSTR=196 floats: rows 16B-aligned (196*4=784, 784%16==0) and stride in
//    16B superbanks = 49 (odd) -> per-lane-row b128 access distributes evenly
//    across all 8 LDS superbanks (no conflict beyond BW minimum).
//  - GEMM phases read x/xd rows as wave-uniform b128 broadcasts (conflict-free).
//  - Weight loads: lane = output channel d0 -> 64x4B coalesced, L2-resident.

#define XSTR 196

__global__ __launch_bounds__(256, 1)
void wmsa_fused(const float* __restrict__ x,
                const float* __restrict__ Wq, const float* __restrict__ bq,
                const float* __restrict__ Wk, const float* __restrict__ bk,
                const float* __restrict__ Wv, const float* __restrict__ bv,
                const float* __restrict__ Wo, const float* __restrict__ bo,
                const float* __restrict__ rt,
                float* __restrict__ out)
{
    __shared__ alignas(16) float s_xw[64 * XSTR];   // rolled window tokens; reused as attn output
    __shared__ alignas(16) float s_q [64 * XSTR];   // Q (64 x 192)
    __shared__ alignas(16) float s_k [16 * 192];    // K
    __shared__ alignas(16) float s_v [16 * 192];    // V
    __shared__ alignas(16) float s_xd[16 * 192];    // max-pooled tokens
    __shared__ alignas(16) float s_rt[6 * 225];     // rel_table (6 x 15 x 15)

    const int tid  = threadIdx.x;
    const int widx = blockIdx.x;
    const int b  = widx >> 10;
    const int wh = (widx >> 5) & 31;
    const int wc = widx & 31;

    // ---------------- Phase 0: load rolled window + rel_table ----------------
    // roll(x, -4): rolled[r] = x[(r+4) mod 256]
    for (int idx = tid; idx < 64 * 48; idx += 256) {
        const int pix = idx / 48;
        const int c4  = idx - pix * 48;
        const int i = pix >> 3, j = pix & 7;
        const int row = (wh * 8 + i + 4) & 255;
        const int col = (wc * 8 + j + 4) & 255;
        const float4 v = *reinterpret_cast<const float4*>(
            x + ((size_t)((b * 256 + row) * 256 + col)) * 192 + c4 * 4);
        *reinterpret_cast<float4*>(&s_xw[pix * XSTR + c4 * 4]) = v;
    }
    for (int idx = tid; idx < 6 * 225; idx += 256) s_rt[idx] = rt[idx];
    __syncthreads();

    // ---------------- Phase 1: 2x2 max-pool -> s_xd (16 x 192) ----------------
    for (int idx = tid; idx < 16 * 192; idx += 256) {
        const int kv = idx / 192;
        const int c  = idx - kv * 192;
        const int ki = kv >> 2, kj = kv & 3;
        const int p0 = (2 * ki) * 8 + 2 * kj;   // pixel (2ki, 2kj)
        const float m0 = fmaxf(s_xw[p0 * XSTR + c],       s_xw[(p0 + 1) * XSTR + c]);
        const float m1 = fmaxf(s_xw[(p0 + 8) * XSTR + c], s_xw[(p0 + 9) * XSTR + c]);
        s_xd[kv * 192 + c] = fmaxf(m0, m1);
    }
    __syncthreads();

    const int d0 = tid & 63;   // output-channel lane (coalesced weight loads)
    const int rg = tid >> 6;   // wave id -> row group (wave-uniform)

    // ---------------- Phase 2a: Q = xw @ Wq + bq (rows rg*16..+15) ----------------
    {
        const int r0 = rg * 16;
        float acc[3][16];
        #pragma unroll
        for (int ct = 0; ct < 3; ++ct) {
            const float bb = bq[ct * 64 + d0];
            #pragma unroll
            for (int rr = 0; rr < 16; ++rr) acc[ct][rr] = bb;
        }
        for (int c4 = 0; c4 < 48; ++c4) {
            float4 xv[16];
            #pragma unroll
            for (int rr = 0; rr < 16; ++rr)   // wave-uniform b128 broadcast reads
                xv[rr] = *reinterpret_cast<const float4*>(&s_xw[(r0 + rr) * XSTR + c4 * 4]);
            #pragma unroll
            for (int cc = 0; cc < 4; ++cc) {
                const int c = c4 * 4 + cc;
                #pragma unroll
                for (int ct = 0; ct < 3; ++ct) {
                    const float w = Wq[c * 192 + ct * 64 + d0];
                    #pragma unroll
                    for (int rr = 0; rr < 16; ++rr) {
                        const float xs = (cc == 0) ? xv[rr].x : (cc == 1) ? xv[rr].y
                                       : (cc == 2) ? xv[rr].z : xv[rr].w;
                        acc[ct][rr] = fmaf(xs, w, acc[ct][rr]);
                    }
                }
            }
        }
        #pragma unroll
        for (int ct = 0; ct < 3; ++ct)
            #pragma unroll
            for (int rr = 0; rr < 16; ++rr)
                s_q[(r0 + rr) * XSTR + ct * 64 + d0] = acc[ct][rr];
    }

    // ---------------- Phase 2b: K,V = xd @ Wk/Wv + b (rows rg*4..+3) ----------------
    {
        const int r0 = rg * 4;
        float ak[3][4], av[3][4];
        #pragma unroll
        for (int ct = 0; ct < 3; ++ct) {
            const float bbk = bk[ct * 64 + d0];
            const float bbv = bv[ct * 64 + d0];
            #pragma unroll
            for (int rr = 0; rr < 4; ++rr) { ak[ct][rr] = bbk; av[ct][rr] = bbv; }
        }
        for (int c4 = 0; c4 < 48; ++c4) {
            float4 xv[4];
            #pragma unroll
            for (int rr = 0; rr < 4; ++rr)
                xv[rr] = *reinterpret_cast<const float4*>(&s_xd[(r0 + rr) * 192 + c4 * 4]);
            #pragma unroll
            for (int cc = 0; cc < 4; ++cc) {
                const int c = c4 * 4 + cc;
                #pragma unroll
                for (int ct = 0; ct < 3; ++ct) {
                    const float wk_ = Wk[c * 192 + ct * 64 + d0];
                    const float wv_ = Wv[c * 192 + ct * 64 + d0];
                    #pragma unroll
                    for (int rr = 0; rr < 4; ++rr) {
                        const float xs = (cc == 0) ? xv[rr].x : (cc == 1) ? xv[rr].y
                                       : (cc == 2) ? xv[rr].z : xv[rr].w;
                        ak[ct][rr] = fmaf(xs, wk_, ak[ct][rr]);
                        av[ct][rr] = fmaf(xs, wv_, av[ct][rr]);
                    }
                }
            }
        }
        #pragma unroll
        for (int ct = 0; ct < 3; ++ct)
            #pragma unroll
            for (int rr = 0; rr < 4; ++rr) {
                s_k[(r0 + rr) * 192 + ct * 64 + d0] = ak[ct][rr];
                s_v[(r0 + rr) * 192 + ct * 64 + d0] = av[ct][rr];
            }
    }
    __syncthreads();

    // ---------------- Phase 3: attention (one thread per (head, query)) ----------------
    // pair = h*64 + p ; lanes within a wave share h (uniform K/V broadcast reads).
    // Writes attention output (64 x 192) over s_xw.
    {
        const float scale = 0.17677669529663687f;  // 32^-0.5
        const bool lastrow = (wh == 31);
        const bool lastcol = (wc == 31);
        #pragma unroll
        for (int pass = 0; pass < 2; ++pass) {
            const int pair = tid + pass * 256;
            if (pair < 384) {
                const int h = pair >> 6;
                const int p = pair & 63;
                const int pi = p >> 3, pj = p & 7;

                float4 q4[8];
                #pragma unroll
                for (int c4 = 0; c4 < 8; ++c4)
                    q4[c4] = *reinterpret_cast<const float4*>(&s_q[p * XSTR + h * 32 + c4 * 4]);

                float sc[16];
                #pragma unroll
                for (int q_ = 0; q_ < 16; ++q_) {
                    float s = 0.f;
                    #pragma unroll
                    for (int c4 = 0; c4 < 8; ++c4) {
                        const float4 k4 = *reinterpret_cast<const float4*>(
                            &s_k[q_ * 192 + h * 32 + c4 * 4]);
                        s = fmaf(q4[c4].x, k4.x, s);
                        s = fmaf(q4[c4].y, k4.y, s);
                        s = fmaf(q4[c4].z, k4.z, s);
                        s = fmaf(q4[c4].w, k4.w, s);
                    }
                    s *= scale;
                    // relative-position bias: key index interpreted with 8-wide coords (ref quirk)
                    const int qi = q_ >> 3, qj = q_ & 7;
                    s += s_rt[h * 225 + (pi - qi + 7) * 15 + (pj - qj + 7)];
                    // shift mask: key-grid coords are 4-wide
                    const int ki = q_ >> 2, kj = q_ & 3;
                    const bool msk = (lastrow && ((pi < 4) != (ki < 2))) ||
                                     (lastcol && ((pj < 4) != (kj < 2)));
                    sc[q_] = msk ? -1e30f : s;
                }

                float m = sc[0];
                #pragma unroll
                for (int q_ = 1; q_ < 16; ++q_) m = fmaxf(m, sc[q_]);
                float sum = 0.f;
                #pragma unroll
                for (int q_ = 0; q_ < 16; ++q_) { sc[q_] = __expf(sc[q_] - m); sum += sc[q_]; }
                const float inv = 1.0f / sum;
                #pragma unroll
                for (int q_ = 0; q_ < 16; ++q_) sc[q_] *= inv;

                // PV: out[p, h*32 + c] = sum_q probs[q] * V[q, h*32 + c]
                #pragma unroll
                for (int c4 = 0; c4 < 8; ++c4) {
                    float ox = 0.f, oy = 0.f, oz = 0.f, ow = 0.f;
                    #pragma unroll
                    for (int q_ = 0; q_ < 16; ++q_) {
                        const float4 v4 = *reinterpret_cast<const float4*>(
                            &s_v[q_ * 192 + h * 32 + c4 * 4]);
                        ox = fmaf(sc[q_], v4.x, ox);
                        oy = fmaf(sc[q_], v4.y, oy);
                        oz = fmaf(sc[q_], v4.z, oz);
                        ow = fmaf(sc[q_], v4.w, ow);
                    }
                    float4 o4; o4.x = ox; o4.y = oy; o4.z = oz; o4.w = ow;
                    *reinterpret_cast<float4*>(&s_xw[p * XSTR + h * 32 + c4 * 4]) = o4;
                }
            }
        }
    }
    __syncthreads();

    // ---------------- Phase 4: O-proj + store (roll back) ----------------
    {
        const int r0 = rg * 16;
        float acc[3][16];
        #pragma unroll
        for (int ct = 0; ct < 3; ++ct) {
            const float bb = bo[ct * 64 + d0];
            #pragma unroll
            for (int rr = 0; rr < 16; ++rr) acc[ct][rr] = bb;
        }
        for (int c4 = 0; c4 < 48; ++c4) {
            float4 xv[16];
            #pragma unroll
            for (int rr = 0; rr < 16; ++rr)
                xv[rr] = *reinterpret_cast<const float4*>(&s_xw[(r0 + rr) * XSTR + c4 * 4]);
            #pragma unroll
            for (int cc = 0; cc < 4; ++cc) {
                const int c = c4 * 4 + cc;
                #pragma unroll
                for (int ct = 0; ct < 3; ++ct) {
                    const float w = Wo[c * 192 + ct * 64 + d0];
                    #pragma unroll
                    for (int rr = 0; rr < 16; ++rr) {
                        const float xs = (cc == 0) ? xv[rr].x : (cc == 1) ? xv[rr].y
                                       : (cc == 2) ? xv[rr].z : xv[rr].w;
                        acc[ct][rr] = fmaf(xs, w, acc[ct][rr]);
                    }
                }
            }
        }
        #pragma unroll
        for (int rr = 0; rr < 16; ++rr) {
            const int p = r0 + rr;
            const int i = p >> 3, j = p & 7;
            const int row = (wh * 8 + i + 4) & 255;
            const int col = (wc * 8 + j + 4) & 255;
            float* dst = out + ((size_t)((b * 256 + row) * 256 + col)) * 192;
            #pragma unroll
            for (int ct = 0; ct < 3; ++ct)
                dst[ct * 64 + d0] = acc[ct][rr];
        }
    }
}

extern "C" void kernel_launch(void* const* d_in, const int* in_sizes, int n_in,
                              void* d_out, int out_size, void* d_ws, size_t ws_size,
                              hipStream_t stream) {
    (void)in_sizes; (void)n_in; (void)out_size; (void)d_ws; (void)ws_size;
    const float* x  = (const float*)d_in[0];
    const float* Wq = (const float*)d_in[1];
    const float* bq = (const float*)d_in[2];
    const float* Wk = (const float*)d_in[3];
    const float* bk = (const float*)d_in[4];
    const float* Wv = (const float*)d_in[5];
    const float* bv = (const float*)d_in[6];
    const float* Wo = (const float*)d_in[7];
    const float* bo = (const float*)d_in[8];
    const float* rt = (const float*)d_in[9];
    float* out = (float*)d_out;

    dim3 grid(4096), block(256);
    hipLaunchKernelGGL(wmsa_fused, grid, block, 0, stream,
                       x, Wq, bq, Wk, bk, Wv, bv, Wo, bo, rt, out);
}

// Round 3
// 1098.022 us; speedup vs baseline: 1.3569x; 1.3569x over previous
//
#include <hip/hip_runtime.h>
#include <cstddef>

// W-MSA fused kernel (Swin-style, shifted window, 2x2 max-pooled K/V).
// One block per window: 4096 blocks x 256 threads, 2 blocks/CU.
// All fp32 (no fp32 MFMA on CDNA4 -> vector ALU GEMMs).
//
// LDS budget (80152 B -> 2 blocks/CU):
//  - s_xw (64 x XSTR) triple-duty: rolled x -> Q (in-place) -> attn out (in-place).
//    Safe because wave rg's pool-reads/Q-reads/Q-writes all live in rows
//    16rg..16rg+15 (stripe-private), and attn thread (h,p) writes exactly the
//    Q channels it read (head-disjoint).
//  - 2x2 max-pool fused into the K/V GEMM (no s_xd buffer).
//  - XSTR=196: rows 16B-aligned, odd superbank stride -> conflict-free
//    per-lane-row b128 in the attention phase (measured: conflicts negligible).

#define XSTR 196

__global__ __launch_bounds__(256, 2)
void wmsa_fused(const float* __restrict__ x,
                const float* __restrict__ Wq, const float* __restrict__ bq,
                const float* __restrict__ Wk, const float* __restrict__ bk,
                const float* __restrict__ Wv, const float* __restrict__ bv,
                const float* __restrict__ Wo, const float* __restrict__ bo,
                const float* __restrict__ rt,
                float* __restrict__ out)
{
    __shared__ alignas(16) float s_xw[64 * XSTR];   // rolled x -> Q -> attn out
    __shared__ alignas(16) float s_k [16 * 192];    // K
    __shared__ alignas(16) float s_v [16 * 192];    // V
    __shared__ alignas(16) float s_rt[6 * 225];     // rel_table (6 x 15 x 15)

    const int tid  = threadIdx.x;
    const int widx = blockIdx.x;
    const int b  = widx >> 10;
    const int wh = (widx >> 5) & 31;
    const int wc = widx & 31;

    // ---------------- Phase 0: load rolled window + rel_table ----------------
    // roll(x, -4): rolled[r] = x[(r+4) mod 256]
    for (int idx = tid; idx < 64 * 48; idx += 256) {
        const int pix = idx / 48;
        const int c4  = idx - pix * 48;
        const int i = pix >> 3, j = pix & 7;
        const int row = (wh * 8 + i + 4) & 255;
        const int col = (wc * 8 + j + 4) & 255;
        const float4 v = *reinterpret_cast<const float4*>(
            x + ((size_t)((b * 256 + row) * 256 + col)) * 192 + c4 * 4);
        *reinterpret_cast<float4*>(&s_xw[pix * XSTR + c4 * 4]) = v;
    }
    for (int idx = tid; idx < 6 * 225; idx += 256) s_rt[idx] = rt[idx];
    __syncthreads();

    const int d0 = tid & 63;   // output-channel lane (coalesced weight loads)
    const int rg = tid >> 6;   // wave id -> row-stripe (wave-uniform)

    // ------- Phase 1: K,V = pool2x2(xw) @ Wk/Wv + b (kv rows rg*4..+3) -------
    // kv = rg*4+rr -> ki=rg, kj=rr -> pixel rows p0,p0+1,p0+8,p0+9 with
    // p0 = rg*16 + 2*rr  (stripe-private to wave rg).
    {
        float ak[3][4], av[3][4];
        #pragma unroll
        for (int ct = 0; ct < 3; ++ct) {
            const float bbk = bk[ct * 64 + d0];
            const float bbv = bv[ct * 64 + d0];
            #pragma unroll
            for (int rr = 0; rr < 4; ++rr) { ak[ct][rr] = bbk; av[ct][rr] = bbv; }
        }
        for (int c4 = 0; c4 < 48; ++c4) {
            float4 xv[4];
            #pragma unroll
            for (int rr = 0; rr < 4; ++rr) {   // fused 2x2 max-pool (uniform)
                const int p0 = rg * 16 + 2 * rr;
                const float4 a = *reinterpret_cast<const float4*>(&s_xw[(p0    ) * XSTR + c4 * 4]);
                const float4 bb= *reinterpret_cast<const float4*>(&s_xw[(p0 + 1) * XSTR + c4 * 4]);
                const float4 c = *reinterpret_cast<const float4*>(&s_xw[(p0 + 8) * XSTR + c4 * 4]);
                const float4 d = *reinterpret_cast<const float4*>(&s_xw[(p0 + 9) * XSTR + c4 * 4]);
                xv[rr].x = fmaxf(fmaxf(a.x, bb.x), fmaxf(c.x, d.x));
                xv[rr].y = fmaxf(fmaxf(a.y, bb.y), fmaxf(c.y, d.y));
                xv[rr].z = fmaxf(fmaxf(a.z, bb.z), fmaxf(c.z, d.z));
                xv[rr].w = fmaxf(fmaxf(a.w, bb.w), fmaxf(c.w, d.w));
            }
            #pragma unroll
            for (int cc = 0; cc < 4; ++cc) {
                const int c = c4 * 4 + cc;
                #pragma unroll
                for (int ct = 0; ct < 3; ++ct) {
                    const float wk_ = Wk[c * 192 + ct * 64 + d0];
                    const float wv_ = Wv[c * 192 + ct * 64 + d0];
                    #pragma unroll
                    for (int rr = 0; rr < 4; ++rr) {
                        const float xs = (cc == 0) ? xv[rr].x : (cc == 1) ? xv[rr].y
                                       : (cc == 2) ? xv[rr].z : xv[rr].w;
                        ak[ct][rr] = fmaf(xs, wk_, ak[ct][rr]);
                        av[ct][rr] = fmaf(xs, wv_, av[ct][rr]);
                    }
                }
            }
        }
        #pragma unroll
        for (int ct = 0; ct < 3; ++ct)
            #pragma unroll
            for (int rr = 0; rr < 4; ++rr) {
                s_k[(rg * 4 + rr) * 192 + ct * 64 + d0] = ak[ct][rr];
                s_v[(rg * 4 + rr) * 192 + ct * 64 + d0] = av[ct][rr];
            }
    }

    // ------- Phase 2: Q = xw @ Wq + bq, IN-PLACE over s_xw (rows rg*16..+15) -------
    // No barrier needed before this: wave rg only reads/writes its own stripe.
    {
        const int r0 = rg * 16;
        float acc[3][16];
        #pragma unroll
        for (int ct = 0; ct < 3; ++ct) {
            const float bb = bq[ct * 64 + d0];
            #pragma unroll
            for (int rr = 0; rr < 16; ++rr) acc[ct][rr] = bb;
        }
        for (int c4 = 0; c4 < 48; ++c4) {
            float4 xv[16];
            #pragma unroll
            for (int rr = 0; rr < 16; ++rr)   // wave-uniform b128 broadcast reads
                xv[rr] = *reinterpret_cast<const float4*>(&s_xw[(r0 + rr) * XSTR + c4 * 4]);
            #pragma unroll
            for (int cc = 0; cc < 4; ++cc) {
                const int c = c4 * 4 + cc;
                #pragma unroll
                for (int ct = 0; ct < 3; ++ct) {
                    const float w = Wq[c * 192 + ct * 64 + d0];
                    #pragma unroll
                    for (int rr = 0; rr < 16; ++rr) {
                        const float xs = (cc == 0) ? xv[rr].x : (cc == 1) ? xv[rr].y
                                       : (cc == 2) ? xv[rr].z : xv[rr].w;
                        acc[ct][rr] = fmaf(xs, w, acc[ct][rr]);
                    }
                }
            }
        }
        #pragma unroll
        for (int ct = 0; ct < 3; ++ct)
            #pragma unroll
            for (int rr = 0; rr < 16; ++rr)
                s_xw[(r0 + rr) * XSTR + ct * 64 + d0] = acc[ct][rr];  // in-place Q
    }
    __syncthreads();

    // ---------------- Phase 3: attention (one thread per (head, query)) ----------------
    // pair = h*64 + p ; lanes within a wave share h (uniform K/V broadcast reads).
    // Reads Q from s_xw, writes attention output IN-PLACE (same (p, head) channels).
    {
        const float scale = 0.17677669529663687f;  // 32^-0.5
        const bool lastrow = (wh == 31);
        const bool lastcol = (wc == 31);
        #pragma unroll
        for (int pass = 0; pass < 2; ++pass) {
            const int pair = tid + pass * 256;
            if (pair < 384) {
                const int h = pair >> 6;
                const int p = pair & 63;
                const int pi = p >> 3, pj = p & 7;

                float4 q4[8];
                #pragma unroll
                for (int c4 = 0; c4 < 8; ++c4)
                    q4[c4] = *reinterpret_cast<const float4*>(&s_xw[p * XSTR + h * 32 + c4 * 4]);

                float sc[16];
                #pragma unroll
                for (int q_ = 0; q_ < 16; ++q_) {
                    float s = 0.f;
                    #pragma unroll
                    for (int c4 = 0; c4 < 8; ++c4) {
                        const float4 k4 = *reinterpret_cast<const float4*>(
                            &s_k[q_ * 192 + h * 32 + c4 * 4]);
                        s = fmaf(q4[c4].x, k4.x, s);
                        s = fmaf(q4[c4].y, k4.y, s);
                        s = fmaf(q4[c4].z, k4.z, s);
                        s = fmaf(q4[c4].w, k4.w, s);
                    }
                    s *= scale;
                    // relative-position bias: key index with 8-wide coords (ref quirk)
                    const int qi = q_ >> 3, qj = q_ & 7;
                    s += s_rt[h * 225 + (pi - qi + 7) * 15 + (pj - qj + 7)];
                    // shift mask: key-grid coords are 4-wide
                    const int ki = q_ >> 2, kj = q_ & 3;
                    const bool msk = (lastrow && ((pi < 4) != (ki < 2))) ||
                                     (lastcol && ((pj < 4) != (kj < 2)));
                    sc[q_] = msk ? -1e30f : s;
                }

                float m = sc[0];
                #pragma unroll
                for (int q_ = 1; q_ < 16; ++q_) m = fmaxf(m, sc[q_]);
                float sum = 0.f;
                #pragma unroll
                for (int q_ = 0; q_ < 16; ++q_) { sc[q_] = __expf(sc[q_] - m); sum += sc[q_]; }
                const float inv = 1.0f / sum;
                #pragma unroll
                for (int q_ = 0; q_ < 16; ++q_) sc[q_] *= inv;

                // PV: out[p, h*32 + c] = sum_q probs[q] * V[q, h*32 + c]
                #pragma unroll
                for (int c4 = 0; c4 < 8; ++c4) {
                    float ox = 0.f, oy = 0.f, oz = 0.f, ow = 0.f;
                    #pragma unroll
                    for (int q_ = 0; q_ < 16; ++q_) {
                        const float4 v4 = *reinterpret_cast<const float4*>(
                            &s_v[q_ * 192 + h * 32 + c4 * 4]);
                        ox = fmaf(sc[q_], v4.x, ox);
                        oy = fmaf(sc[q_], v4.y, oy);
                        oz = fmaf(sc[q_], v4.z, oz);
                        ow = fmaf(sc[q_], v4.w, ow);
                    }
                    float4 o4; o4.x = ox; o4.y = oy; o4.z = oz; o4.w = ow;
                    *reinterpret_cast<float4*>(&s_xw[p * XSTR + h * 32 + c4 * 4]) = o4;
                }
            }
        }
    }
    __syncthreads();

    // ---------------- Phase 4: O-proj + store (roll back) ----------------
    {
        const int r0 = rg * 16;
        float acc[3][16];
        #pragma unroll
        for (int ct = 0; ct < 3; ++ct) {
            const float bb = bo[ct * 64 + d0];
            #pragma unroll
            for (int rr = 0; rr < 16; ++rr) acc[ct][rr] = bb;
        }
        for (int c4 = 0; c4 < 48; ++c4) {
            float4 xv[16];
            #pragma unroll
            for (int rr = 0; rr < 16; ++rr)
                xv[rr] = *reinterpret_cast<const float4*>(&s_xw[(r0 + rr) * XSTR + c4 * 4]);
            #pragma unroll
            for (int cc = 0; cc < 4; ++cc) {
                const int c = c4 * 4 + cc;
                #pragma unroll
                for (int ct = 0; ct < 3; ++ct) {
                    const float w = Wo[c * 192 + ct * 64 + d0];
                    #pragma unroll
                    for (int rr = 0; rr < 16; ++rr) {
                        const float xs = (cc == 0) ? xv[rr].x : (cc == 1) ? xv[rr].y
                                       : (cc == 2) ? xv[rr].z : xv[rr].w;
                        acc[ct][rr] = fmaf(xs, w, acc[ct][rr]);
                    }
                }
            }
        }
        #pragma unroll
        for (int rr = 0; rr < 16; ++rr) {
            const int p = r0 + rr;
            const int i = p >> 3, j = p & 7;
            const int row = (wh * 8 + i + 4) & 255;
            const int col = (wc * 8 + j + 4) & 255;
            float* dst = out + ((size_t)((b * 256 + row) * 256 + col)) * 192;
            #pragma unroll
            for (int ct = 0; ct < 3; ++ct)
                dst[ct * 64 + d0] = acc[ct][rr];
        }
    }
}

extern "C" void kernel_launch(void* const* d_in, const int* in_sizes, int n_in,
                              void* d_out, int out_size, void* d_ws, size_t ws_size,
                              hipStream_t stream) {
    (void)in_sizes; (void)n_in; (void)out_size; (void)d_ws; (void)ws_size;
    const float* x  = (const float*)d_in[0];
    const float* Wq = (const float*)d_in[1];
    const float* bq = (const float*)d_in[2];
    const float* Wk = (const float*)d_in[3];
    const float* bk = (const float*)d_in[4];
    const float* Wv = (const float*)d_in[5];
    const float* bv = (const float*)d_in[6];
    const float* Wo = (const float*)d_in[7];
    const float* bo = (const float*)d_in[8];
    const float* rt = (const float*)d_in[9];
    float* out = (float*)d_out;

    dim3 grid(4096), block(256);
    hipLaunchKernelGGL(wmsa_fused, grid, block, 0, stream,
                       x, Wq, bq, Wk, bk, Wv, bv, Wo, bo, rt, out);
}

// Round 9
// 652.939 us; speedup vs baseline: 2.2818x; 1.6817x over previous
//
#include <hip/hip_runtime.h>
#include <cstddef>

// W-MSA fused kernel: projections on MFMA (split-bf16 3-pass), attention on fp32 VALU.
// Prep kernel pre-swizzles weights into MFMA B-fragment layout (hi/lo bf16) in d_ws.
// Main: 4096 blocks x 256 threads, 2 blocks/CU (LDS 80152 B).
//
// MFMA 16x16x32 bf16 layouts (verified mappings, learn_hip m89/m91):
//   A: lane l holds A[row = l&15][k = (l>>4)*8 + j], j=0..7
//   B: lane l holds B[k = (l>>4)*8 + j][col = l&15]
//   C/D: lane l, reg r -> row = (l>>4)*4 + r, col = l&15
// Note: any consistent within-instruction k-slot permutation cancels between
// A and B fragments; only the row/col and C/D mappings must match hardware.
// Split-bf16: x = hi(x) + lo(x); x@W ~= xh@Wh + xl@Wh + xh@Wl (lo*lo dropped).

#define XSTR 196

typedef __attribute__((ext_vector_type(8))) short s16x8;   // 8 bf16 (4 VGPRs)
typedef __attribute__((ext_vector_type(4))) float f32x4;   // MFMA acc

__device__ __forceinline__ short f2bf(float f) {           // RNE fp32 -> bf16
    unsigned u = __float_as_uint(f);
    u = u + 0x7fffu + ((u >> 16) & 1u);
    return (short)(u >> 16);
}
__device__ __forceinline__ float bf2f(short h) {
    return __uint_as_float(((unsigned)(unsigned short)h) << 16);
}

// d_ws layout (shorts): [mat(4)][hi|lo][ct(12)][kc(6)][lane(64)][8]
#define MAT_S 73728
#define LO_S  36864
#define CT_S   3072
#define KC_S    512

__global__ __launch_bounds__(256)
void prep_w(const float* __restrict__ Wq, const float* __restrict__ Wk,
            const float* __restrict__ Wv, const float* __restrict__ Wo,
            unsigned short* __restrict__ ws)
{
    const int t = blockIdx.x * 256 + threadIdx.x;
    if (t >= 4 * 12 * 6 * 64) return;
    const int lane = t & 63;
    const int kc = (t >> 6) % 6;
    const int ct = (t / 384) % 12;
    const int m  = t / 4608;
    const float* W = (m == 0) ? Wq : (m == 1) ? Wk : (m == 2) ? Wv : Wo;
    const int n  = ct * 16 + (lane & 15);
    const int k0 = kc * 32 + ((lane >> 4) * 8);
    alignas(16) unsigned short hi[8];
    alignas(16) unsigned short lo[8];
    #pragma unroll
    for (int j = 0; j < 8; ++j) {
        const float f = W[(size_t)(k0 + j) * 192 + n];
        const short h = f2bf(f);
        hi[j] = (unsigned short)h;
        lo[j] = (unsigned short)f2bf(f - bf2f(h));
    }
    unsigned short* dst = ws + (size_t)m * MAT_S + ct * CT_S + kc * KC_S + lane * 8;
    *reinterpret_cast<uint4*>(dst)        = *reinterpret_cast<const uint4*>(hi);
    *reinterpret_cast<uint4*>(dst + LO_S) = *reinterpret_cast<const uint4*>(lo);
}

__global__ __launch_bounds__(256, 2)
void wmsa_fused(const float* __restrict__ x,
                const float* __restrict__ bq, const float* __restrict__ bk,
                const float* __restrict__ bv, const float* __restrict__ bo,
                const float* __restrict__ rt,
                const unsigned short* __restrict__ ws,
                float* __restrict__ out)
{
    __shared__ alignas(16) float s_xw[64 * XSTR];   // rolled x -> Q -> attn out
    __shared__ alignas(16) float s_k [16 * 192];
    __shared__ alignas(16) float s_v [16 * 192];
    __shared__ alignas(16) float s_rt[6 * 225];

    const int tid  = threadIdx.x;
    const int widx = blockIdx.x;
    const int b  = widx >> 10;
    const int wh = (widx >> 5) & 31;
    const int wc = widx & 31;

    // ---- Phase 0: load rolled window (roll -4,-4) + rel_table ----
    for (int idx = tid; idx < 64 * 48; idx += 256) {
        const int pix = idx / 48;
        const int c4  = idx - pix * 48;
        const int i = pix >> 3, j = pix & 7;
        const int row = (wh * 8 + i + 4) & 255;
        const int col = (wc * 8 + j + 4) & 255;
        const float4 v = *reinterpret_cast<const float4*>(
            x + ((size_t)((b * 256 + row) * 256 + col)) * 192 + c4 * 4);
        *reinterpret_cast<float4*>(&s_xw[pix * XSTR + c4 * 4]) = v;
    }
    for (int idx = tid; idx < 6 * 225; idx += 256) s_rt[idx] = rt[idx];
    __syncthreads();

    const int lane = tid & 63;
    const int w    = tid >> 6;
    const int wm   = w >> 1;        // M-half (rows 32*wm..) for Q/O
    const int wn   = w & 1;         // N-half (ct 6*wn..)    for Q/O
    const int g    = lane >> 4;     // k-group within fragment
    const int c15  = lane & 15;

    // ---- KV A-fragments: pooled xd[kv=c15][k], fused 2x2 max-pool ----
    // kv=c15 -> ki=c15>>2, kj=c15&3 -> pixels (2ki,2kj),(2ki,2kj+1),(2ki+1,2kj),(2ki+1,2kj+1)
    s16x8 kah[6], kal[6];
    {
        const int p0 = (c15 >> 2) * 16 + (c15 & 3) * 2;
        const float* r0 = &s_xw[(p0    ) * XSTR];
        const float* r1 = &s_xw[(p0 + 1) * XSTR];
        const float* r2 = &s_xw[(p0 + 8) * XSTR];
        const float* r3 = &s_xw[(p0 + 9) * XSTR];
        #pragma unroll
        for (int kc = 0; kc < 6; ++kc) {
            const int cb = kc * 32 + g * 8;
            #pragma unroll
            for (int j = 0; j < 8; ++j) {
                const float f = fmaxf(fmaxf(r0[cb + j], r1[cb + j]),
                                      fmaxf(r2[cb + j], r3[cb + j]));
                const short h = f2bf(f);
                kah[kc][j] = h;
                kal[kc][j] = f2bf(f - bf2f(h));
            }
        }
    }

    // ---- K/V GEMM (MFMA): waves 0,1 -> K (ct 0..5 / 6..11); waves 2,3 -> V ----
    {
        const int isV = (w >> 1) & 1;
        const unsigned short* wsm = ws + (size_t)(1 + isV) * MAT_S;
        const float* bias = isV ? bv : bk;
        float* sdst = isV ? s_v : s_k;
        const int ct0 = (w & 1) * 6;
        #pragma unroll
        for (int ctl = 0; ctl < 6; ++ctl) {
            const int ct = ct0 + ctl;
            const unsigned short* bp = wsm + ct * CT_S + lane * 8;
            f32x4 a0 = {0.f,0.f,0.f,0.f}, a1 = a0, a2 = a0;
            #pragma unroll
            for (int kc = 0; kc < 6; ++kc) {
                const s16x8 bh = *reinterpret_cast<const s16x8*>(bp + kc * KC_S);
                const s16x8 bl = *reinterpret_cast<const s16x8*>(bp + kc * KC_S + LO_S);
                a0 = __builtin_amdgcn_mfma_f32_16x16x32_bf16(kah[kc], bh, a0, 0, 0, 0);
                a1 = __builtin_amdgcn_mfma_f32_16x16x32_bf16(kal[kc], bh, a1, 0, 0, 0);
                a2 = __builtin_amdgcn_mfma_f32_16x16x32_bf16(kah[kc], bl, a2, 0, 0, 0);
            }
            const float bb = bias[ct * 16 + c15];
            #pragma unroll
            for (int r = 0; r < 4; ++r)     // C: col=c15, row=g*4+r
                sdst[(g * 4 + r) * 192 + ct * 16 + c15] = a0[r] + a1[r] + a2[r] + bb;
        }
    }

    // ---- Q A-fragments (rows 32*wm..+31; s_xw still holds original x) ----
    s16x8 qah[2][6], qal[2][6];
    #pragma unroll
    for (int mt = 0; mt < 2; ++mt) {
        const int rb = wm * 32 + mt * 16 + c15;
        #pragma unroll
        for (int kc = 0; kc < 6; ++kc) {
            const float* src = &s_xw[rb * XSTR + kc * 32 + g * 8];
            #pragma unroll
            for (int j = 0; j < 8; ++j) {
                const float f = src[j];
                const short h = f2bf(f);
                qah[mt][kc][j] = h;
                qal[mt][kc][j] = f2bf(f - bf2f(h));
            }
        }
    }
    __syncthreads();   // all A-frags built -> s_xw may be overwritten

    // ---- Q GEMM (MFMA), in-place into s_xw (disjoint row/col tiles per wave) ----
    {
        #pragma unroll
        for (int ctl = 0; ctl < 6; ++ctl) {
            const int ct = wn * 6 + ctl;
            const unsigned short* bp = ws + ct * CT_S + lane * 8;   // Wq = mat 0
            const float bb = bq[ct * 16 + c15];
            #pragma unroll
            for (int mt = 0; mt < 2; ++mt) {
                f32x4 a0 = {0.f,0.f,0.f,0.f}, a1 = a0, a2 = a0;
                #pragma unroll
                for (int kc = 0; kc < 6; ++kc) {
                    const s16x8 bh = *reinterpret_cast<const s16x8*>(bp + kc * KC_S);
                    const s16x8 bl = *reinterpret_cast<const s16x8*>(bp + kc * KC_S + LO_S);
                    a0 = __builtin_amdgcn_mfma_f32_16x16x32_bf16(qah[mt][kc], bh, a0, 0, 0, 0);
                    a1 = __builtin_amdgcn_mfma_f32_16x16x32_bf16(qal[mt][kc], bh, a1, 0, 0, 0);
                    a2 = __builtin_amdgcn_mfma_f32_16x16x32_bf16(qah[mt][kc], bl, a2, 0, 0, 0);
                }
                #pragma unroll
                for (int r = 0; r < 4; ++r) {
                    const int p = wm * 32 + mt * 16 + g * 4 + r;
                    s_xw[p * XSTR + ct * 16 + c15] = a0[r] + a1[r] + a2[r] + bb;
                }
            }
        }
    }
    __syncthreads();

    // ---- Attention: fp32 VALU, one thread per (head, query) ----
    {
        const float scale = 0.17677669529663687f;  // 32^-0.5
        const bool lastrow = (wh == 31);
        const bool lastcol = (wc == 31);
        #pragma unroll
        for (int pass = 0; pass < 2; ++pass) {
            const int pair = tid + pass * 256;
            if (pair < 384) {
                const int h = pair >> 6;
                const int p = pair & 63;
                const int pi = p >> 3, pj = p & 7;

                float4 q4[8];
                #pragma unroll
                for (int c4 = 0; c4 < 8; ++c4)
                    q4[c4] = *reinterpret_cast<const float4*>(&s_xw[p * XSTR + h * 32 + c4 * 4]);

                float sc[16];
                #pragma unroll
                for (int q_ = 0; q_ < 16; ++q_) {
                    float s = 0.f;
                    #pragma unroll
                    for (int c4 = 0; c4 < 8; ++c4) {
                        const float4 k4 = *reinterpret_cast<const float4*>(
                            &s_k[q_ * 192 + h * 32 + c4 * 4]);
                        s = fmaf(q4[c4].x, k4.x, s);
                        s = fmaf(q4[c4].y, k4.y, s);
                        s = fmaf(q4[c4].z, k4.z, s);
                        s = fmaf(q4[c4].w, k4.w, s);
                    }
                    s *= scale;
                    const int qi = q_ >> 3, qj = q_ & 7;     // bias quirk: 8-wide coords
                    s += s_rt[h * 225 + (pi - qi + 7) * 15 + (pj - qj + 7)];
                    const int ki = q_ >> 2, kj = q_ & 3;     // mask: 4-wide coords
                    const bool msk = (lastrow && ((pi < 4) != (ki < 2))) ||
                                     (lastcol && ((pj < 4) != (kj < 2)));
                    sc[q_] = msk ? -1e30f : s;
                }

                float m = sc[0];
                #pragma unroll
                for (int q_ = 1; q_ < 16; ++q_) m = fmaxf(m, sc[q_]);
                float sum = 0.f;
                #pragma unroll
                for (int q_ = 0; q_ < 16; ++q_) { sc[q_] = __expf(sc[q_] - m); sum += sc[q_]; }
                const float inv = 1.0f / sum;
                #pragma unroll
                for (int q_ = 0; q_ < 16; ++q_) sc[q_] *= inv;

                #pragma unroll
                for (int c4 = 0; c4 < 8; ++c4) {
                    float ox = 0.f, oy = 0.f, oz = 0.f, ow = 0.f;
                    #pragma unroll
                    for (int q_ = 0; q_ < 16; ++q_) {
                        const float4 v4 = *reinterpret_cast<const float4*>(
                            &s_v[q_ * 192 + h * 32 + c4 * 4]);
                        ox = fmaf(sc[q_], v4.x, ox);
                        oy = fmaf(sc[q_], v4.y, oy);
                        oz = fmaf(sc[q_], v4.z, oz);
                        ow = fmaf(sc[q_], v4.w, ow);
                    }
                    float4 o4; o4.x = ox; o4.y = oy; o4.z = oz; o4.w = ow;
                    *reinterpret_cast<float4*>(&s_xw[p * XSTR + h * 32 + c4 * 4]) = o4;
                }
            }
        }
    }
    __syncthreads();

    // ---- O A-fragments from attention output ----
    s16x8 oah[2][6], oal[2][6];
    #pragma unroll
    for (int mt = 0; mt < 2; ++mt) {
        const int rb = wm * 32 + mt * 16 + c15;
        #pragma unroll
        for (int kc = 0; kc < 6; ++kc) {
            const float* src = &s_xw[rb * XSTR + kc * 32 + g * 8];
            #pragma unroll
            for (int j = 0; j < 8; ++j) {
                const float f = src[j];
                const short h = f2bf(f);
                oah[mt][kc][j] = h;
                oal[mt][kc][j] = f2bf(f - bf2f(h));
            }
        }
    }

    // ---- O GEMM (MFMA) + store with roll-back (+4,+4) ----
    {
        const unsigned short* wsm = ws + (size_t)3 * MAT_S;   // Wo = mat 3
        #pragma unroll
        for (int ctl = 0; ctl < 6; ++ctl) {
            const int ct = wn * 6 + ctl;
            const unsigned short* bp = wsm + ct * CT_S + lane * 8;
            const float bb = bo[ct * 16 + c15];
            #pragma unroll
            for (int mt = 0; mt < 2; ++mt) {
                f32x4 a0 = {0.f,0.f,0.f,0.f}, a1 = a0, a2 = a0;
                #pragma unroll
                for (int kc = 0; kc < 6; ++kc) {
                    const s16x8 bh = *reinterpret_cast<const s16x8*>(bp + kc * KC_S);
                    const s16x8 bl = *reinterpret_cast<const s16x8*>(bp + kc * KC_S + LO_S);
                    a0 = __builtin_amdgcn_mfma_f32_16x16x32_bf16(oah[mt][kc], bh, a0, 0, 0, 0);
                    a1 = __builtin_amdgcn_mfma_f32_16x16x32_bf16(oal[mt][kc], bh, a1, 0, 0, 0);
                    a2 = __builtin_amdgcn_mfma_f32_16x16x32_bf16(oah[mt][kc], bl, a2, 0, 0, 0);
                }
                #pragma unroll
                for (int r = 0; r < 4; ++r) {
                    const int p = wm * 32 + mt * 16 + g * 4 + r;
                    const int i = p >> 3, j = p & 7;
                    const int row = (wh * 8 + i + 4) & 255;
                    const int col = (wc * 8 + j + 4) & 255;
                    out[((size_t)((b * 256 + row) * 256 + col)) * 192 + ct * 16 + c15] =
                        a0[r] + a1[r] + a2[r] + bb;
                }
            }
        }
    }
}

extern "C" void kernel_launch(void* const* d_in, const int* in_sizes, int n_in,
                              void* d_out, int out_size, void* d_ws, size_t ws_size,
                              hipStream_t stream) {
    (void)in_sizes; (void)n_in; (void)out_size; (void)ws_size;
    const float* x  = (const float*)d_in[0];
    const float* Wq = (const float*)d_in[1];
    const float* bq = (const float*)d_in[2];
    const float* Wk = (const float*)d_in[3];
    const float* bk = (const float*)d_in[4];
    const float* Wv = (const float*)d_in[5];
    const float* bv = (const float*)d_in[6];
    const float* Wo = (const float*)d_in[7];
    const float* bo = (const float*)d_in[8];
    const float* rt = (const float*)d_in[9];
    float* out = (float*)d_out;
    unsigned short* ws = (unsigned short*)d_ws;   // needs 589824 B

    hipLaunchKernelGGL(prep_w, dim3(72), dim3(256), 0, stream, Wq, Wk, Wv, Wo, ws);
    hipLaunchKernelGGL(wmsa_fused, dim3(4096), dim3(256), 0, stream,
                       x, bq, bk, bv, bo, rt, ws, out);
}